// Round 3
// baseline (236.672 us; speedup 1.0000x reference)
//
#include <hip/hip_runtime.h>
#include <math.h>

#define WIDTH   512
#define NPLANE  48          // 16 batch * 3 channels
#define TILE    32
#define HALO    5
#define NROWS   42          // TILE + 2*HALO
#define SSTR    44          // input tile LDS row stride (floats)
#define HSTR    36          // hbuf LDS row stride (floats)
#define NBLOCKS (16*16*NPLANE)   // 12288
#define NPIX    (16.0*3.0*512.0*512.0)

struct GaussW { float w[11]; };

// blur 16 contiguous outputs from a 28-float window, write 4xfloat4 to dst
__device__ __forceinline__ void blur16(const float* vin, const GaussW& gw, float* dst)
{
    #pragma unroll
    for (int q4 = 0; q4 < 4; ++q4) {
        float o[4];
        #pragma unroll
        for (int t = 0; t < 4; ++t) {
            int ci = q4 * 4 + t;
            float s = vin[ci] * gw.w[0];
            #pragma unroll
            for (int k = 1; k < 11; ++k) s = fmaf(gw.w[k], vin[ci + k], s);
            o[t] = s;
        }
        *reinterpret_cast<float4*>(dst + 4 * q4) = make_float4(o[0], o[1], o[2], o[3]);
    }
}

__global__ __launch_bounds__(256)
void ssim_tile_kernel(const float* __restrict__ img1,
                      const float* __restrict__ img2,
                      float* __restrict__ partial, GaussW gw)
{
    __shared__ __align__(16) float s1[NROWS][SSTR];
    __shared__ __align__(16) float s2[NROWS][SSTR];
    __shared__ __align__(16) float hb[5][NROWS][HSTR];
    __shared__ float red[4];

    const int tid   = threadIdx.x;
    const int gx0   = blockIdx.x * TILE - HALO;
    const int gy0   = blockIdx.y * TILE - HALO;
    const int plane = blockIdx.z;

    const float* __restrict__ p1 = img1 + (size_t)plane * (WIDTH * WIDTH);
    const float* __restrict__ p2 = img2 + (size_t)plane * (WIDTH * WIDTH);

    // ---- stage both input tiles (zero-padded halo) ----
    for (int l = tid; l < NROWS * SSTR; l += 256) {
        int r = l / SSTR, c = l - r * SSTR;
        int gx = gx0 + c, gy = gy0 + r;
        bool ok = ((unsigned)gx < WIDTH) && ((unsigned)gy < WIDTH);
        int idx = gy * WIDTH + gx;
        s1[r][c] = ok ? p1[idx] : 0.f;
        s2[r][c] = ok ? p2[idx] : 0.f;
    }
    __syncthreads();

    // ---- ONE horizontal pass, all 5 quantities ----
    // item = (r*2 + cg)*3 + g ; r in [0,42), cg in {0,1}, g in {0,1,2}
    // g0: mu1h + s11h from img1 ; g1: mu2h + s22h from img2 ; g2: s12h from both
    if (tid < 252) {
        int g  = tid % 3;
        int t2 = tid / 3;
        int cg = t2 & 1;
        int r  = t2 >> 1;
        int c0 = cg << 4;
        float va[28], vb[28];
        if (g != 1) {
            #pragma unroll
            for (int p = 0; p < 7; ++p) {
                float4 v = *reinterpret_cast<const float4*>(&s1[r][c0 + 4 * p]);
                va[4*p+0]=v.x; va[4*p+1]=v.y; va[4*p+2]=v.z; va[4*p+3]=v.w;
            }
        }
        if (g != 0) {
            #pragma unroll
            for (int p = 0; p < 7; ++p) {
                float4 v = *reinterpret_cast<const float4*>(&s2[r][c0 + 4 * p]);
                vb[4*p+0]=v.x; vb[4*p+1]=v.y; vb[4*p+2]=v.z; vb[4*p+3]=v.w;
            }
        }
        if (g == 0) {
            blur16(va, gw, &hb[0][r][c0]);
            #pragma unroll
            for (int i = 0; i < 28; ++i) va[i] = va[i] * va[i];
            blur16(va, gw, &hb[2][r][c0]);
        } else if (g == 1) {
            blur16(vb, gw, &hb[1][r][c0]);
            #pragma unroll
            for (int i = 0; i < 28; ++i) vb[i] = vb[i] * vb[i];
            blur16(vb, gw, &hb[3][r][c0]);
        } else {
            #pragma unroll
            for (int i = 0; i < 28; ++i) va[i] = va[i] * vb[i];
            blur16(va, gw, &hb[4][r][c0]);
        }
    }
    __syncthreads();

    // ---- ONE vertical pass: thread owns (col c, 4 rows), all 5 quantities ----
    const int c  = tid & 31;
    const int r0 = (tid >> 5) << 2;
    float acc[5][4];
    #pragma unroll
    for (int q = 0; q < 5; ++q) {
        float win[14];
        #pragma unroll
        for (int j = 0; j < 14; ++j) win[j] = hb[q][r0 + j][c];
        #pragma unroll
        for (int i = 0; i < 4; ++i) {
            float s = win[i] * gw.w[0];
            #pragma unroll
            for (int k = 1; k < 11; ++k) s = fmaf(gw.w[k], win[i + k], s);
            acc[q][i] = s;
        }
    }

    // ---- SSIM map + per-thread sum ----
    const float C1 = 0.01f * 0.01f;
    const float C2 = 0.03f * 0.03f;
    float ssum = 0.f;
    #pragma unroll
    for (int i = 0; i < 4; ++i) {
        float a  = acc[0][i], b = acc[1][i];
        float ab = a * b, a2 = a * a, b2 = b * b;
        float s11 = acc[2][i] - a2;
        float s22 = acc[3][i] - b2;
        float s12 = acc[4][i] - ab;
        float num = (2.f * ab + C1) * (2.f * s12 + C2);
        float den = (a2 + b2 + C1) * (s11 + s22 + C2);
        ssum += num / den;
    }

    // ---- block reduction (deterministic) ----
    #pragma unroll
    for (int off = 32; off > 0; off >>= 1) ssum += __shfl_down(ssum, off);
    int wid = tid >> 6, lane = tid & 63;
    if (lane == 0) red[wid] = ssum;
    __syncthreads();
    if (tid == 0) {
        int bid = blockIdx.x + 16 * (blockIdx.y + 16 * blockIdx.z);
        partial[bid] = red[0] + red[1] + red[2] + red[3];
    }
}

__global__ __launch_bounds__(1024)
void ssim_reduce_kernel(const float* __restrict__ partial, float* __restrict__ out)
{
    __shared__ double red[16];
    double s = 0.0;
    for (int i = threadIdx.x; i < NBLOCKS; i += 1024) s += (double)partial[i];
    #pragma unroll
    for (int off = 32; off > 0; off >>= 1) s += __shfl_down(s, off);
    if ((threadIdx.x & 63) == 0) red[threadIdx.x >> 6] = s;
    __syncthreads();
    if (threadIdx.x == 0) {
        double t = 0.0;
        #pragma unroll
        for (int w = 0; w < 16; ++w) t += red[w];
        out[0] = (float)(t / NPIX);
    }
}

extern "C" void kernel_launch(void* const* d_in, const int* in_sizes, int n_in,
                              void* d_out, int out_size, void* d_ws, size_t ws_size,
                              hipStream_t stream)
{
    GaussW gw;
    double g[11], sum = 0.0;
    for (int i = 0; i < 11; ++i) {
        double x = (double)(i - 5);
        g[i] = exp(-(x * x) / 4.5);
        sum += g[i];
    }
    for (int i = 0; i < 11; ++i) gw.w[i] = (float)(g[i] / sum);

    const float* img1 = (const float*)d_in[0];
    const float* img2 = (const float*)d_in[1];
    float* partial = (float*)d_ws;   // NBLOCKS floats; every slot written each launch
    float* out = (float*)d_out;

    dim3 grid(16, 16, NPLANE);
    hipLaunchKernelGGL(ssim_tile_kernel, grid, dim3(256), 0, stream,
                       img1, img2, partial, gw);
    hipLaunchKernelGGL(ssim_reduce_kernel, dim3(1), dim3(1024), 0, stream,
                       partial, out);
}

// Round 4
// 186.028 us; speedup vs baseline: 1.2722x; 1.2722x over previous
//
#include <hip/hip_runtime.h>
#include <math.h>

#define WIDTH   512
#define NPLANE  48          // 16 batch * 3 channels
#define TILE    32
#define HALO    5
#define NROWS   42          // TILE + 2*HALO
#define SSTR    52          // staged input row stride (words): 48 cols + 4 pad
#define HBS     48          // hb per-column row-slot count
#define GRIDX   16
#define NBLOCKS (GRIDX*GRIDX*NPLANE)
#define NPIX    (16.0*3.0*512.0*512.0)

struct GaussW { float w[11]; };

// staging tiles and transposed h-blur buffer share LDS (overlay, separated
// by a barrier): s = 17472 B, hb = 30720 B -> union 30720 B -> 5 blocks/CU
union SU {
    float s[2][NROWS][SSTR];
    float hb[5 * 32 * HBS];   // [q][col][row ^ ((col&3)<<2)]
};

__device__ __forceinline__ void blur16(const float* vin, const GaussW& gw, float* o)
{
    #pragma unroll
    for (int t = 0; t < 16; ++t) {
        float s = vin[t] * gw.w[0];
        #pragma unroll
        for (int k = 1; k < 11; ++k) s = fmaf(gw.w[k], vin[t + k], s);
        o[t] = s;
    }
}

__global__ __launch_bounds__(256, 4)
void ssim_tile_kernel(const float* __restrict__ img1,
                      const float* __restrict__ img2,
                      float* __restrict__ partial, GaussW gw)
{
    __shared__ __align__(16) SU su;
    __shared__ float red[4];

    const int tid = threadIdx.x;
    const int bx = blockIdx.x, by = blockIdx.y, bz = blockIdx.z;
    const float* __restrict__ p1 = img1 + (size_t)bz * (WIDTH * WIDTH);
    const float* __restrict__ p2 = img2 + (size_t)bz * (WIDTH * WIDTH);
    const int gx0 = bx * TILE - 8;      // first staged col (float4-aligned)
    const int gy0 = by * TILE - HALO;   // first staged row

    const bool interior = ((unsigned)(bx - 1) < 14u) & ((unsigned)(by - 1) < 14u);

    // ---- stage: 2 imgs x 42 rows x 12 float4 = 1008 vector loads ----
    if (interior) {
        #pragma unroll
        for (int k = 0; k < 4; ++k) {
            int l = tid + (k << 8);
            if (l < 1008) {
                int img = l >= 504;
                int u2  = img ? l - 504 : l;
                int r   = u2 / 12;
                int p   = u2 - r * 12;
                const float* gp = (img ? p2 : p1) + (gy0 + r) * WIDTH + (gx0 + (p << 2));
                *(float4*)&su.s[img][r][p << 2] = *(const float4*)gp;
            }
        }
    } else {
        #pragma unroll
        for (int k = 0; k < 4; ++k) {
            int l = tid + (k << 8);
            if (l < 1008) {
                int img = l >= 504;
                int u2  = img ? l - 504 : l;
                int r   = u2 / 12;
                int p   = u2 - r * 12;
                int gr = gy0 + r, gc = gx0 + (p << 2);
                float4 v = make_float4(0.f, 0.f, 0.f, 0.f);
                if ((unsigned)gr < WIDTH && (unsigned)gc <= (WIDTH - 4))
                    v = *(const float4*)((img ? p2 : p1) + gr * WIDTH + gc);
                *(float4*)&su.s[img][r][p << 2] = v;
            }
        }
    }
    __syncthreads();

    // ---- ONE horizontal pass; g wave-uniform by tid range ----
    // [0,84): img1 -> q0 (mu1h), q2 (s11h); [84,168): img2 -> q1, q3;
    // [168,252): cross -> q4
    const bool active = tid < 252;
    float oa[16], ob[16];
    int qa = 0, qb = 0, r = 0, c0 = 0, g = 0;
    if (active) {
        g = (tid >= 84) + (tid >= 168);
        int u2 = tid - g * 84;
        r  = u2 >> 1;
        c0 = (u2 & 1) << 4;
        float ld[32];
        if (g < 2) {
            const float* sp = &su.s[g][r][c0];
            #pragma unroll
            for (int p = 0; p < 8; ++p) {
                float4 v = *(const float4*)(sp + (p << 2));
                ld[4*p] = v.x; ld[4*p+1] = v.y; ld[4*p+2] = v.z; ld[4*p+3] = v.w;
            }
            blur16(ld + 3, gw, oa);
            #pragma unroll
            for (int i = 0; i < 26; ++i) ld[3 + i] *= ld[3 + i];
            blur16(ld + 3, gw, ob);
            qa = g; qb = g + 2;
        } else {
            float lb[32];
            const float* spa = &su.s[0][r][c0];
            const float* spb = &su.s[1][r][c0];
            #pragma unroll
            for (int p = 0; p < 8; ++p) {
                float4 v = *(const float4*)(spa + (p << 2));
                ld[4*p] = v.x; ld[4*p+1] = v.y; ld[4*p+2] = v.z; ld[4*p+3] = v.w;
                float4 w2 = *(const float4*)(spb + (p << 2));
                lb[4*p] = w2.x; lb[4*p+1] = w2.y; lb[4*p+2] = w2.z; lb[4*p+3] = w2.w;
            }
            #pragma unroll
            for (int i = 0; i < 26; ++i) ld[3 + i] *= lb[3 + i];
            blur16(ld + 3, gw, oa);
            qa = 4;
        }
    }
    __syncthreads();   // all staging reads done -> hb may overwrite s

    if (active) {
        int ba = (qa * 32 + c0) * HBS;
        #pragma unroll
        for (int j = 0; j < 16; ++j)
            su.hb[ba + j * HBS + (r ^ ((j & 3) << 2))] = oa[j];
        if (g < 2) {
            int bb = (qb * 32 + c0) * HBS;
            #pragma unroll
            for (int j = 0; j < 16; ++j)
                su.hb[bb + j * HBS + (r ^ ((j & 3) << 2))] = ob[j];
        }
    }
    __syncthreads();

    // ---- vertical pass: thread = (col c, rows r0..r0+3), all 5 q, b128 reads ----
    const int c   = tid & 31;
    const int r0  = (tid >> 5) << 2;
    const int swz = (c & 3) << 2;
    float acc[5][4];
    #pragma unroll
    for (int q = 0; q < 5; ++q) {
        const int base = (q * 32 + c) * HBS;
        float win[16];
        #pragma unroll
        for (int k = 0; k < 4; ++k) {
            int rr = (r0 + (k << 2)) ^ swz;
            float4 v = *(const float4*)&su.hb[base + rr];
            win[4*k] = v.x; win[4*k+1] = v.y; win[4*k+2] = v.z; win[4*k+3] = v.w;
        }
        #pragma unroll
        for (int i = 0; i < 4; ++i) {
            float s = win[i] * gw.w[0];
            #pragma unroll
            for (int k = 1; k < 11; ++k) s = fmaf(gw.w[k], win[i + k], s);
            acc[q][i] = s;
        }
    }

    // ---- SSIM map + reduction ----
    const float C1 = 0.01f * 0.01f, C2 = 0.03f * 0.03f;
    float ssum = 0.f;
    #pragma unroll
    for (int i = 0; i < 4; ++i) {
        float a = acc[0][i], b = acc[1][i];
        float ab = a * b, a2 = a * a, b2 = b * b;
        float s11 = acc[2][i] - a2;
        float s22 = acc[3][i] - b2;
        float s12 = acc[4][i] - ab;
        float num = (2.f * ab + C1) * (2.f * s12 + C2);
        float den = (a2 + b2 + C1) * (s11 + s22 + C2);
        ssum += num / den;
    }

    #pragma unroll
    for (int off = 32; off > 0; off >>= 1) ssum += __shfl_down(ssum, off);
    if ((tid & 63) == 0) red[tid >> 6] = ssum;
    __syncthreads();
    if (tid == 0)
        partial[bx + GRIDX * (by + GRIDX * bz)] = red[0] + red[1] + red[2] + red[3];
}

__global__ __launch_bounds__(1024)
void ssim_reduce_kernel(const float* __restrict__ partial, float* __restrict__ out)
{
    __shared__ double red[16];
    double s = 0.0;
    for (int i = threadIdx.x; i < NBLOCKS; i += 1024) s += (double)partial[i];
    #pragma unroll
    for (int off = 32; off > 0; off >>= 1) s += __shfl_down(s, off);
    if ((threadIdx.x & 63) == 0) red[threadIdx.x >> 6] = s;
    __syncthreads();
    if (threadIdx.x == 0) {
        double t = 0.0;
        #pragma unroll
        for (int w = 0; w < 16; ++w) t += red[w];
        out[0] = (float)(t / NPIX);
    }
}

extern "C" void kernel_launch(void* const* d_in, const int* in_sizes, int n_in,
                              void* d_out, int out_size, void* d_ws, size_t ws_size,
                              hipStream_t stream)
{
    GaussW gw;
    double g[11], sum = 0.0;
    for (int i = 0; i < 11; ++i) {
        double x = (double)(i - 5);
        g[i] = exp(-(x * x) / 4.5);
        sum += g[i];
    }
    for (int i = 0; i < 11; ++i) gw.w[i] = (float)(g[i] / sum);

    const float* img1 = (const float*)d_in[0];
    const float* img2 = (const float*)d_in[1];
    float* partial = (float*)d_ws;   // NBLOCKS floats; every slot written each launch
    float* out = (float*)d_out;

    dim3 grid(GRIDX, GRIDX, NPLANE);
    hipLaunchKernelGGL(ssim_tile_kernel, grid, dim3(256), 0, stream,
                       img1, img2, partial, gw);
    hipLaunchKernelGGL(ssim_reduce_kernel, dim3(1), dim3(1024), 0, stream,
                       partial, out);
}